// Round 12
// baseline (1335.734 us; speedup 1.0000x reference)
//
#include <hip/hip_runtime.h>
#include <hip/hip_bf16.h>
#include <stdint.h>

typedef __attribute__((ext_vector_type(8))) __bf16 bf16x8;
typedef __attribute__((ext_vector_type(4))) float f32x4;
typedef __attribute__((ext_vector_type(4))) int   i32x4;

#define BM 128
#define BN 128
#define BK 64

__device__ inline void gload_lds16(const void* g, void* l) {
    __builtin_amdgcn_global_load_lds(
        (const __attribute__((address_space(1))) uint32_t*)g,
        (__attribute__((address_space(3))) uint32_t*)l, 16, 0, 0);
}

// ---------------- pass 1a: X f32 -> per-row int8 + scale ----------------
__global__ __launch_bounds__(256)
void quant_x(const float* __restrict__ X, int8_t* __restrict__ Xq,
             float* __restrict__ sx, int K) {
    const int row = blockIdx.x;
    const int tid = threadIdx.x;
    const float* base = X + (size_t)row * K;
    __shared__ float wred[4];

    float am = 0.f;
    for (int b = tid * 16; b < K; b += 256 * 16) {
#pragma unroll
        for (int c = 0; c < 4; ++c) {
            const float4 v = *(const float4*)(base + b + c * 4);
            am = fmaxf(am, fmaxf(fmaxf(fabsf(v.x), fabsf(v.y)),
                                 fmaxf(fabsf(v.z), fabsf(v.w))));
        }
    }
#pragma unroll
    for (int off = 32; off >= 1; off >>= 1)
        am = fmaxf(am, __shfl_xor(am, off));
    if ((tid & 63) == 0) wred[tid >> 6] = am;
    __syncthreads();
    am = fmaxf(fmaxf(wred[0], wred[1]), fmaxf(wred[2], wred[3]));

    const float inv = am > 0.f ? 127.f / am : 0.f;
    for (int b = tid * 16; b < K; b += 256 * 16) {
        int w[4];
#pragma unroll
        for (int c = 0; c < 4; ++c) {
            const float4 v = *(const float4*)(base + b + c * 4);
            const int b0 = __float2int_rn(v.x * inv) & 0xFF;
            const int b1 = __float2int_rn(v.y * inv) & 0xFF;
            const int b2 = __float2int_rn(v.z * inv) & 0xFF;
            const int b3 = __float2int_rn(v.w * inv) & 0xFF;
            w[c] = b0 | (b1 << 8) | (b2 << 16) | (b3 << 24);
        }
        *(int4*)(Xq + (size_t)row * K + b) = make_int4(w[0], w[1], w[2], w[3]);
    }
    if (tid == 0) sx[row] = am > 0.f ? am / 127.f : 0.f;
}

// ---------------- pass 1b: W -> int8 (q - z), exact ----------------
__global__ __launch_bounds__(128)
void quant_w(const int* __restrict__ QW, const int* __restrict__ QZ,
             int8_t* __restrict__ Wq, int N, int K) {
    const int PQ = K >> 3, NG = K >> 7, ZS = (NG + 7) >> 3;
    const int o = blockIdx.x;
    const int c = threadIdx.x;            // 0..K/32-1
    const int g = c >> 2;
    const int zq = (QZ[(size_t)o * ZS + (g >> 3)] >> ((g & 7) * 4)) & 15;
    const int4 qv = *(const int4*)(QW + (size_t)o * PQ + c * 4);
    const int vs[4] = {qv.x, qv.y, qv.z, qv.w};
    int words[8];
#pragma unroll
    for (int w = 0; w < 4; ++w) {
        const int v = vs[w];
        int w0 = 0, w1 = 0;
#pragma unroll
        for (int j = 0; j < 4; ++j)
            w0 |= ((((v >> (4 * j)) & 15) - zq) & 0xFF) << (8 * j);
#pragma unroll
        for (int j = 0; j < 4; ++j)
            w1 |= ((((v >> (4 * (j + 4))) & 15) - zq) & 0xFF) << (8 * j);
        words[w * 2] = w0; words[w * 2 + 1] = w1;
    }
    int8_t* dst = Wq + (size_t)o * K + c * 32;
    *(int4*)dst        = make_int4(words[0], words[1], words[2], words[3]);
    *(int4*)(dst + 16) = make_int4(words[4], words[5], words[6], words[7]);
}

// ---------------- pass 1c: scales [O][NG] f32 -> [NG][O] ----------------
__global__ __launch_bounds__(256)
void tr_s(const float* __restrict__ S, float* __restrict__ St, int N, int NG) {
    const int idx = blockIdx.x * 256 + threadIdx.x;
    if (idx >= N * NG) return;
    const int g = idx / N, o = idx % N;
    St[idx] = S[(size_t)o * NG + g];
}

// ---------------- pass 2: i8 GEMM v3 ----------------
// Block 256x128, 512 thr = 8 waves (4 wm x 2 wn), wave tile 64x64 (r9-verified).
// K-tile 64, group = 2 tiles = 128 K = one AWQ group. Ring-4 LDS (4 x 24KB)
// + per-block scale table (16KB, all NG groups x 128 cols) = 112 KB.
// Scales read from LDS (lgkm domain) -> vmcnt FIFO holds ONLY staging loads:
// 3 loads/tile, top gate vmcnt(3) every tile, vmcnt(0) only at final tile.
// Fine-grained merge: in odd tile's 16-MFMA cluster, merge(acc j-1) is issued
// between MFMA j and j+1 -> merge VALU (~256 cyc) overlaps MFMA pipe (~256 cyc).
// Swizzle chunk^((row>>1)&3), pre-swizzled global src (r6/r11: 0 conflicts).
__global__ __launch_bounds__(512, 1)
void gemm_i8v3(const int8_t* __restrict__ Aq, const float* __restrict__ sx,
               const int8_t* __restrict__ Bq, const float* __restrict__ St,
               const float* __restrict__ Bi, float* __restrict__ Out,
               int M, int N, int K) {
    __shared__ __align__(16) char lds[4 * 24576 + 16384];   // 112 KB
    float* sTab = (float*)(lds + 98304);

    const int tid  = threadIdx.x;
    const int lane = tid & 63;
    const int wid  = tid >> 6;
    const int wm   = wid >> 1;   // 0..3
    const int wn   = wid & 1;    // 0..1

    int bid = blockIdx.x;
    {
        const int nwg = gridDim.x;
        if ((nwg & 7) == 0) {
            const int cpx = nwg >> 3;
            bid = (bid & 7) * cpx + (bid >> 3);
        }
    }
    const int nbm  = M / 256;
    const int brow = (bid % nbm) * 256;   // col-major tile order
    const int bcol = (bid / nbm) * 128;

    const int NGRP = K >> 7;              // host guarantees even, 4..32
    const int NT   = NGRP * 2;

    // staging: A 1024 16B-slots (2/thread: s=tid, s=tid+512), B 512 (1/thread).
    // slot s: row=s>>2, c_lds=s&3, global chunk c_g = (s&3)^((s>>3)&3).
    const int sro = tid >> 2;
    const int scg = (tid & 3) ^ ((tid >> 3) & 3);
    const int8_t* gA0 = Aq + (size_t)(brow + sro) * K + scg * 16;
    const int8_t* gA1 = gA0 + (size_t)128 * K;   // slot tid+512: same chunk, row+128
    const int8_t* gB0 = Bq + (size_t)(bcol + sro) * K + scg * 16;
    const int lb = wid * 1024;            // wave-uniform LDS byte base (HW adds lane*16)

    const int rA15 = lane & 15;
    const int q4   = lane >> 4;
    const int chunkoff = (q4 ^ ((rA15 >> 1) & 3)) * 16;

    // ---- prologue: scale table -> LDS, then first two tiles in flight ----
    for (int i = tid; i < NGRP * 128; i += 512)
        sTab[i] = St[(size_t)(i >> 7) * N + bcol + (i & 127)];

#define SBAR __builtin_amdgcn_sched_barrier(0)
#define ABASE(RR_) (lds + (RR_) * 24576)
#define BBASE(RR_) (lds + (RR_) * 24576 + 16384)

#define STAGE(RR_, T_)                                                   \
    do {                                                                 \
        gload_lds16(gA0 + (size_t)(T_) * 64, ABASE(RR_) + lb);           \
        gload_lds16(gA1 + (size_t)(T_) * 64, ABASE(RR_) + 8192 + lb);    \
        gload_lds16(gB0 + (size_t)(T_) * 64, BBASE(RR_) + lb);           \
    } while (0)

#define LDA(RR_, MI) \
    (*(const i32x4*)(ABASE(RR_) + (wm * 64 + (MI) * 16 + rA15) * 64 + chunkoff))
#define LDB(RR_, NI) \
    (*(const i32x4*)(BBASE(RR_) + (wn * 64 + (NI) * 16 + rA15) * 64 + chunkoff))

    STAGE(0, 0);
    STAGE(1, 1);
    asm volatile("s_waitcnt lgkmcnt(0)" ::: "memory"); SBAR;
    __builtin_amdgcn_s_barrier(); SBAR;

    f32x4 facc[4][4];
#pragma unroll
    for (int i = 0; i < 4; ++i)
#pragma unroll
        for (int j = 0; j < 4; ++j)
            facc[i][j] = {0.f, 0.f, 0.f, 0.f};
    i32x4 iacc[4][4];

// even tile: 16 MFMA, FIRST (overwrite iacc)
#define TILE_E(RR_, VM_, STG_)                                           \
    do {                                                                 \
        asm volatile("s_waitcnt vmcnt(" VM_ ")" ::: "memory"); SBAR;     \
        __builtin_amdgcn_s_barrier(); SBAR;                              \
        STG_; SBAR;                                                      \
        i32x4 a0 = LDA(RR_, 0), a1 = LDA(RR_, 1);                        \
        i32x4 a2 = LDA(RR_, 2), a3 = LDA(RR_, 3);                        \
        i32x4 b0 = LDB(RR_, 0), b1 = LDB(RR_, 1);                        \
        i32x4 b2 = LDB(RR_, 2), b3 = LDB(RR_, 3);                        \
        asm volatile("s_waitcnt lgkmcnt(0)" ::: "memory"); SBAR;         \
        __builtin_amdgcn_s_setprio(1);                                   \
        const i32x4 zz = {0, 0, 0, 0};                                   \
        iacc[0][0] = __builtin_amdgcn_mfma_i32_16x16x64_i8(a0, b0, zz, 0, 0, 0); \
        iacc[0][1] = __builtin_amdgcn_mfma_i32_16x16x64_i8(a0, b1, zz, 0, 0, 0); \
        iacc[0][2] = __builtin_amdgcn_mfma_i32_16x16x64_i8(a0, b2, zz, 0, 0, 0); \
        iacc[0][3] = __builtin_amdgcn_mfma_i32_16x16x64_i8(a0, b3, zz, 0, 0, 0); \
        iacc[1][0] = __builtin_amdgcn_mfma_i32_16x16x64_i8(a1, b0, zz, 0, 0, 0); \
        iacc[1][1] = __builtin_amdgcn_mfma_i32_16x16x64_i8(a1, b1, zz, 0, 0, 0); \
        iacc[1][2] = __builtin_amdgcn_mfma_i32_16x16x64_i8(a1, b2, zz, 0, 0, 0); \
        iacc[1][3] = __builtin_amdgcn_mfma_i32_16x16x64_i8(a1, b3, zz, 0, 0, 0); \
        iacc[2][0] = __builtin_amdgcn_mfma_i32_16x16x64_i8(a2, b0, zz, 0, 0, 0); \
        iacc[2][1] = __builtin_amdgcn_mfma_i32_16x16x64_i8(a2, b1, zz, 0, 0, 0); \
        iacc[2][2] = __builtin_amdgcn_mfma_i32_16x16x64_i8(a2, b2, zz, 0, 0, 0); \
        iacc[2][3] = __builtin_amdgcn_mfma_i32_16x16x64_i8(a2, b3, zz, 0, 0, 0); \
        iacc[3][0] = __builtin_amdgcn_mfma_i32_16x16x64_i8(a3, b0, zz, 0, 0, 0); \
        iacc[3][1] = __builtin_amdgcn_mfma_i32_16x16x64_i8(a3, b1, zz, 0, 0, 0); \
        iacc[3][2] = __builtin_amdgcn_mfma_i32_16x16x64_i8(a3, b2, zz, 0, 0, 0); \
        iacc[3][3] = __builtin_amdgcn_mfma_i32_16x16x64_i8(a3, b3, zz, 0, 0, 0); \
        __builtin_amdgcn_s_setprio(0); SBAR;                             \
    } while (0)

#define MM(MI_, NI_) \
    iacc[MI_][NI_] = __builtin_amdgcn_mfma_i32_16x16x64_i8(a##MI_, b##NI_, iacc[MI_][NI_], 0, 0, 0)
#define MG(MI_, NI_)                                                     \
    do {                                                                 \
        _Pragma("unroll")                                                \
        for (int j = 0; j < 4; ++j)                                      \
            facc[MI_][NI_][j] += (float)iacc[MI_][NI_][j] * sv[NI_];     \
    } while (0)

// odd tile: accumulate + interleaved merge (group G_ complete after this tile)
#define TILE_O(RR_, G_, VM_, STG_)                                       \
    do {                                                                 \
        asm volatile("s_waitcnt vmcnt(" VM_ ")" ::: "memory"); SBAR;     \
        __builtin_amdgcn_s_barrier(); SBAR;                              \
        STG_; SBAR;                                                      \
        i32x4 a0 = LDA(RR_, 0), a1 = LDA(RR_, 1);                        \
        i32x4 a2 = LDA(RR_, 2), a3 = LDA(RR_, 3);                        \
        i32x4 b0 = LDB(RR_, 0), b1 = LDB(RR_, 1);                        \
        i32x4 b2 = LDB(RR_, 2), b3 = LDB(RR_, 3);                        \
        float sv[4];                                                     \
        sv[0] = sTab[(G_) * 128 + wn * 64 +  0 + rA15];                  \
        sv[1] = sTab[(G_) * 128 + wn * 64 + 16 + rA15];                  \
        sv[2] = sTab[(G_) * 128 + wn * 64 + 32 + rA15];                  \
        sv[3] = sTab[(G_) * 128 + wn * 64 + 48 + rA15];                  \
        asm volatile("s_waitcnt lgkmcnt(0)" ::: "memory"); SBAR;         \
        __builtin_amdgcn_s_setprio(1);                                   \
        MM(0, 0);                                                        \
        MM(0, 1); MG(0, 0);                                              \
        MM(0, 2); MG(0, 1);                                              \
        MM(0, 3); MG(0, 2);                                              \
        MM(1, 0); MG(0, 3);                                              \
        MM(1, 1); MG(1, 0);                                              \
        MM(1, 2); MG(1, 1);                                              \
        MM(1, 3); MG(1, 2);                                              \
        MM(2, 0); MG(1, 3);                                              \
        MM(2, 1); MG(2, 0);                                              \
        MM(2, 2); MG(2, 1);                                              \
        MM(2, 3); MG(2, 2);                                              \
        MM(3, 0); MG(2, 3);                                              \
        MM(3, 1); MG(3, 0);                                              \
        MM(3, 2); MG(3, 1);                                              \
        MM(3, 3); MG(3, 2);                                              \
        MG(3, 3);                                                        \
        __builtin_amdgcn_s_setprio(0); SBAR;                             \
    } while (0)

    // group 0: tiles 0,1 (rings 0,1); stage tiles 2,3
    TILE_E(0,    "3", STAGE(2, 2));
    TILE_O(1, 0, "3", STAGE(3, 3));

    // steady pairs: groups g(odd, rings 2,3) and g+1(even, rings 0,1)
    for (int g = 1; g + 1 < NGRP - 1; g += 2) {
        const int t = 2 * g;
        TILE_E(2,        "3", STAGE(0, t + 2));
        TILE_O(3, g,     "3", STAGE(1, t + 3));
        TILE_E(0,        "3", STAGE(2, t + 4));
        TILE_O(1, g + 1, "3", STAGE(3, t + 5));
    }

    // peeled last group NGRP-1 (odd, rings 2,3): no staging, drain
    TILE_E(2,            "3", (void)0);
    TILE_O(3, NGRP - 1,  "0", (void)0);

#undef TILE_O
#undef MG
#undef MM
#undef TILE_E
#undef LDB
#undef LDA
#undef STAGE
#undef BBASE
#undef ABASE
#undef SBAR

    // epilogue (r9-verified): C frag col=lane&15, row=(lane>>4)*4+r
    const int cr0 = brow + wm * 64;
    const int cc0 = bcol + wn * 64;
#pragma unroll
    for (int ni = 0; ni < 4; ++ni) {
        const int col = cc0 + ni * 16 + rA15;
        const float bv = Bi[col];
#pragma unroll
        for (int mi = 0; mi < 4; ++mi) {
#pragma unroll
            for (int r = 0; r < 4; ++r) {
                const int row = cr0 + mi * 16 + q4 * 4 + r;
                Out[(size_t)row * N + col] = sx[row] * facc[mi][ni][r] + bv;
            }
        }
    }
}

// ---------------- fallback: fused kernel (ws too small / odd shapes) ----------------
__global__ __launch_bounds__(256, 3)
void awq_gemm_fused(const float* __restrict__ X,
                    const int* __restrict__ QW,
                    const int* __restrict__ QZ,
                    const float* __restrict__ S,
                    const float* __restrict__ Bi,
                    float* __restrict__ Out,
                    int M, int N, int K) {
    const int PQ = K >> 3, NG = K >> 7, ZS = (NG + 7) >> 3;

    __shared__ __align__(16) __bf16 As[BM * BK];
    __shared__ __align__(16) __bf16 Bs[BN * BK];

    const int tid  = threadIdx.x;
    const int lane = tid & 63;
    const int wid  = tid >> 6;

    const int nwg = gridDim.x;
    int bid = blockIdx.x;
    if ((nwg & 7) == 0) {
        const int cpx = nwg >> 3;
        bid = (bid & 7) * cpx + (bid >> 3);
    }
    const int nbn  = N / BN;
    const int brow = (bid / nbn) * BM;
    const int bcol = (bid % nbn) * BN;

    const int wm = wid >> 1;
    const int wn = wid & 1;

    f32x4 acc[4][4];
#pragma unroll
    for (int i = 0; i < 4; ++i)
#pragma unroll
        for (int j = 0; j < 4; ++j)
            acc[i][j] = {0.f, 0.f, 0.f, 0.f};

    int arow[4], acch[4];
#pragma unroll
    for (int it = 0; it < 4; ++it) {
        const int idx = it * 256 + tid;
        arow[it] = idx >> 3;
        acch[it] = idx & 7;
    }

    const int rb    = tid >> 1;
    const int bhalf = tid & 1;
    const int og    = bcol + rb;
    const int* qwrow = QW + (size_t)og * PQ;
    const int* qzrow = QZ + (size_t)og * ZS;
    const float* srow = S + (size_t)og * NG;

    for (int kk = 0; kk < K; kk += BK) {
        bf16x8 areg[4];
#pragma unroll
        for (int it = 0; it < 4; ++it) {
            const float* gx = X + (size_t)(brow + arow[it]) * K + kk + acch[it] * 8;
            const float4 x0 = *(const float4*)gx;
            const float4 x1 = *(const float4*)(gx + 4);
            areg[it][0] = (__bf16)x0.x; areg[it][1] = (__bf16)x0.y;
            areg[it][2] = (__bf16)x0.z; areg[it][3] = (__bf16)x0.w;
            areg[it][4] = (__bf16)x1.x; areg[it][5] = (__bf16)x1.y;
            areg[it][6] = (__bf16)x1.z; areg[it][7] = (__bf16)x1.w;
        }

        const int4 qv = *(const int4*)(qwrow + (kk >> 3) + bhalf * 4);
        const int g  = kk >> 7;
        const int zq = (qzrow[g >> 3] >> ((g & 7) * 4)) & 15;
        const float sf = srow[g];
        const float zs = (float)zq * sf;
        const int vs[4] = {qv.x, qv.y, qv.z, qv.w};
        bf16x8 wregs[4];
#pragma unroll
        for (int w = 0; w < 4; ++w) {
            const int v = vs[w];
#pragma unroll
            for (int j = 0; j < 8; ++j) {
                const float q = (float)((v >> (4 * j)) & 15);
                wregs[w][j] = (__bf16)(q * sf - zs);
            }
        }

#pragma unroll
        for (int it = 0; it < 4; ++it) {
            const int cs = acch[it] ^ (arow[it] & 7);
            *((bf16x8*)(As + (size_t)arow[it] * BK + cs * 8)) = areg[it];
        }
#pragma unroll
        for (int w = 0; w < 4; ++w) {
            const int cs = (bhalf * 4 + w) ^ (rb & 7);
            *((bf16x8*)(Bs + (size_t)rb * BK + cs * 8)) = wregs[w];
        }

        __syncthreads();

#pragma unroll
        for (int ks = 0; ks < 2; ++ks) {
            bf16x8 af[4], bfr[4];
#pragma unroll
            for (int mi = 0; mi < 4; ++mi) {
                const int row = wm * 64 + mi * 16 + (lane & 15);
                const int cs  = (ks * 4 + (lane >> 4)) ^ (row & 7);
                af[mi] = *((const bf16x8*)(As + (size_t)row * BK + cs * 8));
            }
#pragma unroll
            for (int ni = 0; ni < 4; ++ni) {
                const int row = wn * 64 + ni * 16 + (lane & 15);
                const int cs  = (ks * 4 + (lane >> 4)) ^ (row & 7);
                bfr[ni] = *((const bf16x8*)(Bs + (size_t)row * BK + cs * 8));
            }
#pragma unroll
            for (int mi = 0; mi < 4; ++mi)
#pragma unroll
                for (int ni = 0; ni < 4; ++ni)
                    acc[mi][ni] = __builtin_amdgcn_mfma_f32_16x16x32_bf16(
                        af[mi], bfr[ni], acc[mi][ni], 0, 0, 0);
        }
        __syncthreads();
    }

    const int cr0 = brow + wm * 64;
    const int cc0 = bcol + wn * 64;
#pragma unroll
    for (int ni = 0; ni < 4; ++ni) {
        const int col = cc0 + ni * 16 + (lane & 15);
        const float bv = Bi[col];
#pragma unroll
        for (int mi = 0; mi < 4; ++mi) {
#pragma unroll
            for (int r = 0; r < 4; ++r) {
                const int row = cr0 + mi * 16 + (lane >> 4) * 4 + r;
                Out[(size_t)row * N + col] = acc[mi][ni][r] + bv;
            }
        }
    }
}

extern "C" void kernel_launch(void* const* d_in, const int* in_sizes, int n_in,
                              void* d_out, int out_size, void* d_ws, size_t ws_size,
                              hipStream_t stream) {
    const float* X  = (const float*)d_in[0];
    const int*   QW = (const int*)d_in[1];
    const int*   QZ = (const int*)d_in[2];
    const float* S  = (const float*)d_in[3];
    const float* Bi = (const float*)d_in[4];
    float*       Out = (float*)d_out;

    const int O = in_sizes[4];           // 11008
    const int K = in_sizes[1] / O * 8;   // 4096
    const int M = in_sizes[0] / K;       // 8192
    const int NG = K / 128;

    // ws layout: Xq [M*K i8] | sx [M f32] | Wq [O*K i8] | St [NG*O f32]
    const size_t oXq = 0;
    const size_t oSx = (size_t)M * K;
    const size_t oWq = oSx + (size_t)M * 4;
    const size_t oSt = oWq + (size_t)O * K;
    const size_t need = oSt + (size_t)NG * O * 4;

    const bool shapes_ok = (M % 256 == 0) && (O % 128 == 0) &&
                           (K % 256 == 0) && (NG >= 4) && (NG <= 32) &&
                           (oWq % 16 == 0) && (oSt % 16 == 0);

    if (ws_size >= need && shapes_ok) {
        int8_t* Xq = (int8_t*)d_ws + oXq;
        float*  sx = (float*)((char*)d_ws + oSx);
        int8_t* Wq = (int8_t*)d_ws + oWq;
        float*  St = (float*)((char*)d_ws + oSt);
        quant_x<<<M, 256, 0, stream>>>(X, Xq, sx, K);
        quant_w<<<O, K / 32, 0, stream>>>(QW, QZ, Wq, O, K);
        tr_s<<<(O * NG + 255) / 256, 256, 0, stream>>>(S, St, O, NG);
        const int grid = (M / 256) * (O / 128);   // 32*86 = 2752
        gemm_i8v3<<<grid, 512, 0, stream>>>(Xq, sx, Wq, St, Bi, Out, M, O, K);
    } else {
        const int grid = (M / BM) * (O / BN);
        awq_gemm_fused<<<grid, 256, 0, stream>>>(X, QW, QZ, S, Bi, Out, M, O, K);
    }
}

// Round 14
// 755.137 us; speedup vs baseline: 1.7689x; 1.7689x over previous
//
#include <hip/hip_runtime.h>
#include <hip/hip_bf16.h>
#include <stdint.h>

typedef __attribute__((ext_vector_type(8))) __bf16 bf16x8;
typedef __attribute__((ext_vector_type(4))) float f32x4;
typedef __attribute__((ext_vector_type(4))) int   i32x4;
typedef __attribute__((ext_vector_type(16))) int   i32x16;
typedef __attribute__((ext_vector_type(16))) float f32x16;

#define BM 128
#define BN 128
#define BK 64

__device__ inline void gload_lds16(const void* g, void* l) {
    __builtin_amdgcn_global_load_lds(
        (const __attribute__((address_space(1))) uint32_t*)g,
        (__attribute__((address_space(3))) uint32_t*)l, 16, 0, 0);
}

// ---------------- pass 1a: X f32 -> per-row int8 + scale ----------------
__global__ __launch_bounds__(256)
void quant_x(const float* __restrict__ X, int8_t* __restrict__ Xq,
             float* __restrict__ sx, int K) {
    const int row = blockIdx.x;
    const int tid = threadIdx.x;
    const float* base = X + (size_t)row * K;
    __shared__ float wred[4];

    float am = 0.f;
    for (int b = tid * 16; b < K; b += 256 * 16) {
#pragma unroll
        for (int c = 0; c < 4; ++c) {
            const float4 v = *(const float4*)(base + b + c * 4);
            am = fmaxf(am, fmaxf(fmaxf(fabsf(v.x), fabsf(v.y)),
                                 fmaxf(fabsf(v.z), fabsf(v.w))));
        }
    }
#pragma unroll
    for (int off = 32; off >= 1; off >>= 1)
        am = fmaxf(am, __shfl_xor(am, off));
    if ((tid & 63) == 0) wred[tid >> 6] = am;
    __syncthreads();
    am = fmaxf(fmaxf(wred[0], wred[1]), fmaxf(wred[2], wred[3]));

    const float inv = am > 0.f ? 127.f / am : 0.f;
    for (int b = tid * 16; b < K; b += 256 * 16) {
        int w[4];
#pragma unroll
        for (int c = 0; c < 4; ++c) {
            const float4 v = *(const float4*)(base + b + c * 4);
            const int b0 = __float2int_rn(v.x * inv) & 0xFF;
            const int b1 = __float2int_rn(v.y * inv) & 0xFF;
            const int b2 = __float2int_rn(v.z * inv) & 0xFF;
            const int b3 = __float2int_rn(v.w * inv) & 0xFF;
            w[c] = b0 | (b1 << 8) | (b2 << 16) | (b3 << 24);
        }
        *(int4*)(Xq + (size_t)row * K + b) = make_int4(w[0], w[1], w[2], w[3]);
    }
    if (tid == 0) sx[row] = am > 0.f ? am / 127.f : 0.f;
}

// ---------------- pass 1b: W -> int8 (q - z), exact ----------------
__global__ __launch_bounds__(128)
void quant_w(const int* __restrict__ QW, const int* __restrict__ QZ,
             int8_t* __restrict__ Wq, int N, int K) {
    const int PQ = K >> 3, NG = K >> 7, ZS = (NG + 7) >> 3;
    const int o = blockIdx.x;
    const int c = threadIdx.x;            // 0..K/32-1
    const int g = c >> 2;
    const int zq = (QZ[(size_t)o * ZS + (g >> 3)] >> ((g & 7) * 4)) & 15;
    const int4 qv = *(const int4*)(QW + (size_t)o * PQ + c * 4);
    const int vs[4] = {qv.x, qv.y, qv.z, qv.w};
    int words[8];
#pragma unroll
    for (int w = 0; w < 4; ++w) {
        const int v = vs[w];
        int w0 = 0, w1 = 0;
#pragma unroll
        for (int j = 0; j < 4; ++j)
            w0 |= ((((v >> (4 * j)) & 15) - zq) & 0xFF) << (8 * j);
#pragma unroll
        for (int j = 0; j < 4; ++j)
            w1 |= ((((v >> (4 * (j + 4))) & 15) - zq) & 0xFF) << (8 * j);
        words[w * 2] = w0; words[w * 2 + 1] = w1;
    }
    int8_t* dst = Wq + (size_t)o * K + c * 32;
    *(int4*)dst        = make_int4(words[0], words[1], words[2], words[3]);
    *(int4*)(dst + 16) = make_int4(words[4], words[5], words[6], words[7]);
}

// ---------------- pass 1c: scales [O][NG] f32 -> [NG][O] ----------------
__global__ __launch_bounds__(256)
void tr_s(const float* __restrict__ S, float* __restrict__ St, int N, int NG) {
    const int idx = blockIdx.x * 256 + threadIdx.x;
    if (idx >= N * NG) return;
    const int g = idx / N, o = idx % N;
    St[idx] = S[(size_t)o * NG + g];
}

// ---------------- pass 2: i8 GEMM v4 (32x32x32 MFMA) ----------------
// Block 256x128, 512 thr = 8 waves (4 wm x 2 wn), wave tile 64x64 = 2x2 frags
// of 32x32. mfma_i32_32x32x32_i8 (4404 TOPS): halves LDS reads per FLOP vs
// 16x16x64 -> LDS pipe no longer binds at 4 waves/SIMD.
// K-tile 64 (2 ksteps of K=32); group = 2 tiles = 128 K = one AWQ group;
// iacc (i32x16 x4) accumulates over the group, one phase-separated f32 merge
// per group (r9's allocator-friendly shape - r12's interleave spilled).
// LDS ring-3 x (A 256x64 = 16KB + B 128x64 = 8KB) = 72KB -> 2 blocks/CU:
// independent blocks overlap merge-VALU with MFMA across blocks.
// Ring rotation by pointer swap (no runtime-indexed array -> no scratch).
// vmcnt FIFO (audited): steady queue at TILE_E top = 6 {t(3), t+1(3)};
// TILE_E: vmcnt(3), sv(2)+stage(3) -> 8. TILE_O: vmcnt(5), stage(3) -> 8,
// merge gate vmcnt(6) retires sv. Drain only in peeled last group.
// Swizzle: 64B rows, chunk^((row>>1)&3) (r11-family, measured 0 conflicts);
// pre-swizzled global source, linear gload_lds dest, swizzled reads.
__global__ __launch_bounds__(512, 2)
void gemm_i8v4(const int8_t* __restrict__ Aq, const float* __restrict__ sx,
               const int8_t* __restrict__ Bq, const float* __restrict__ St,
               const float* __restrict__ Bi, float* __restrict__ Out,
               int M, int N, int K) {
    __shared__ __align__(16) char lds[3 * 24576];   // 72 KB

    const int tid  = threadIdx.x;
    const int lane = tid & 63;
    const int wid  = tid >> 6;
    const int wm   = wid >> 1;   // 0..3
    const int wn   = wid & 1;    // 0..1

    int bid = blockIdx.x;
    {
        const int nwg = gridDim.x;
        if ((nwg & 7) == 0) {
            const int cpx = nwg >> 3;
            bid = (bid & 7) * cpx + (bid >> 3);
        }
    }
    const int nbm  = M / 256;
    const int brow = (bid % nbm) * 256;   // col-major tile order
    const int bcol = (bid / nbm) * 128;

    const int NGRP = K >> 7;

    // staging: A 1024 16B-slots (2/thread), B 512 (1/thread).
    // slot s: row=s>>2, c_lds=s&3; global chunk c_g=(s&3)^((s>>3)&3).
    const int sro = tid >> 2;
    const int scg = (tid & 3) ^ ((tid >> 3) & 3);
    const int8_t* gA0 = Aq + (size_t)(brow + sro) * K + scg * 16;
    const int8_t* gA1 = gA0 + (size_t)128 * K;
    const int8_t* gB0 = Bq + (size_t)(bcol + sro) * K + scg * 16;
    const int lb = wid * 1024;            // wave-uniform LDS base (HW adds lane*16)

    const int c32 = lane & 31;            // col within 32-wide frag
    const int q2  = lane >> 5;            // k-half selector
    const int swz = (c32 >> 1) & 3;       // (row>>1)&3 with 32-aligned row bases
    const int koff0 = ((0 * 2 + q2) ^ swz) * 16;   // kstep 0 chunk offset
    const int koff1 = ((1 * 2 + q2) ^ swz) * 16;   // kstep 1 chunk offset

    f32x16 facc[2][2];
#pragma unroll
    for (int i = 0; i < 2; ++i)
#pragma unroll
        for (int j = 0; j < 2; ++j)
#pragma unroll
            for (int r = 0; r < 16; ++r)
                facc[i][j][r] = 0.f;
    i32x16 iacc[2][2];
    float sv0 = 0.f, sv1 = 0.f;

#define SBAR __builtin_amdgcn_sched_barrier(0)

#define STAGE(P_, T_)                                                    \
    do {                                                                 \
        gload_lds16(gA0 + (size_t)(T_) * 64, (P_) + lb);                 \
        gload_lds16(gA1 + (size_t)(T_) * 64, (P_) + 8192 + lb);          \
        gload_lds16(gB0 + (size_t)(T_) * 64, (P_) + 16384 + lb);         \
    } while (0)

#define LDA(P_, MI, KOFF_) \
    (*(const i32x4*)((P_) + (wm * 64 + (MI) * 32 + c32) * 64 + (KOFF_)))
#define LDB(P_, NI, KOFF_) \
    (*(const i32x4*)((P_) + 16384 + (wn * 64 + (NI) * 32 + c32) * 64 + (KOFF_)))

#define KSTEP(P_, KOFF_, FIRST_)                                         \
    do {                                                                 \
        i32x4 a0 = LDA(P_, 0, KOFF_), a1 = LDA(P_, 1, KOFF_);            \
        i32x4 b0 = LDB(P_, 0, KOFF_), b1 = LDB(P_, 1, KOFF_);            \
        asm volatile("s_waitcnt lgkmcnt(0)" ::: "memory"); SBAR;         \
        __builtin_amdgcn_s_setprio(1);                                   \
        if (FIRST_) {                                                    \
            i32x16 zz;                                                   \
            _Pragma("unroll")                                            \
            for (int r = 0; r < 16; ++r) zz[r] = 0;                      \
            iacc[0][0] = __builtin_amdgcn_mfma_i32_32x32x32_i8(a0, b0, zz, 0, 0, 0); \
            iacc[0][1] = __builtin_amdgcn_mfma_i32_32x32x32_i8(a0, b1, zz, 0, 0, 0); \
            iacc[1][0] = __builtin_amdgcn_mfma_i32_32x32x32_i8(a1, b0, zz, 0, 0, 0); \
            iacc[1][1] = __builtin_amdgcn_mfma_i32_32x32x32_i8(a1, b1, zz, 0, 0, 0); \
        } else {                                                         \
            iacc[0][0] = __builtin_amdgcn_mfma_i32_32x32x32_i8(a0, b0, iacc[0][0], 0, 0, 0); \
            iacc[0][1] = __builtin_amdgcn_mfma_i32_32x32x32_i8(a0, b1, iacc[0][1], 0, 0, 0); \
            iacc[1][0] = __builtin_amdgcn_mfma_i32_32x32x32_i8(a1, b0, iacc[1][0], 0, 0, 0); \
            iacc[1][1] = __builtin_amdgcn_mfma_i32_32x32x32_i8(a1, b1, iacc[1][1], 0, 0, 0); \
        }                                                                \
        __builtin_amdgcn_s_setprio(0); SBAR;                             \
    } while (0)

#define TILE_E(P_, G_, STG_)                                             \
    do {                                                                 \
        asm volatile("s_waitcnt vmcnt(3)" ::: "memory"); SBAR;           \
        __builtin_amdgcn_s_barrier(); SBAR;                              \
        const float* sp = St + (size_t)(G_) * N + bcol + wn * 64 + c32;  \
        sv0 = sp[0]; sv1 = sp[32];                                       \
        SBAR; STG_; SBAR;                                                \
        KSTEP(P_, koff0, true);                                          \
        KSTEP(P_, koff1, false);                                         \
    } while (0)

#define TILE_O(P_, STG_, VMTOP_, VMCVT_)                                 \
    do {                                                                 \
        asm volatile("s_waitcnt vmcnt(" VMTOP_ ")" ::: "memory"); SBAR;  \
        __builtin_amdgcn_s_barrier(); SBAR;                              \
        STG_; SBAR;                                                      \
        KSTEP(P_, koff0, false);                                         \
        KSTEP(P_, koff1, false);                                         \
        asm volatile("s_waitcnt vmcnt(" VMCVT_ ")" ::: "memory"); SBAR;  \
        _Pragma("unroll")                                                \
        for (int r = 0; r < 16; ++r) {                                   \
            facc[0][0][r] += (float)iacc[0][0][r] * sv0;                 \
            facc[0][1][r] += (float)iacc[0][1][r] * sv1;                 \
            facc[1][0][r] += (float)iacc[1][0][r] * sv0;                 \
            facc[1][1][r] += (float)iacc[1][1][r] * sv1;                 \
        }                                                                \
    } while (0)

    char* p0 = lds;
    char* p1 = lds + 24576;
    char* p2 = lds + 49152;

    // prologue: tiles 0,1 in flight (queue = 6)
    STAGE(p0, 0);
    STAGE(p1, 1);

    for (int g = 0; g < NGRP - 1; ++g) {
        TILE_E(p0, g, STAGE(p2, 2 * g + 2));
        TILE_O(p1, STAGE(p0, 2 * g + 3), "5", "6");
        char* tmp = p0; p0 = p2; p2 = p1; p1 = tmp;
    }
    // peeled last group: no staging; drain
    TILE_E(p0, NGRP - 1, (void)0);
    TILE_O(p1, (void)0, "2", "0");

#undef TILE_O
#undef TILE_E
#undef KSTEP
#undef LDB
#undef LDA
#undef STAGE
#undef SBAR

    // epilogue: 32x32 C layout col=lane&31, row=(r&3)+8*(r>>2)+4*(lane>>5)
    const int cr = brow + wm * 64;
    const int cc = bcol + wn * 64;
#pragma unroll
    for (int ni = 0; ni < 2; ++ni) {
        const int col = cc + ni * 32 + c32;
        const float bv = Bi[col];
#pragma unroll
        for (int mi = 0; mi < 2; ++mi) {
#pragma unroll
            for (int r = 0; r < 16; ++r) {
                const int row = cr + mi * 32 + (r & 3) + 8 * (r >> 2) + 4 * q2;
                Out[(size_t)row * N + col] = sx[row] * facc[mi][ni][r] + bv;
            }
        }
    }
}

// ---------------- fallback: fused kernel (ws too small / odd shapes) ----------------
__global__ __launch_bounds__(256, 3)
void awq_gemm_fused(const float* __restrict__ X,
                    const int* __restrict__ QW,
                    const int* __restrict__ QZ,
                    const float* __restrict__ S,
                    const float* __restrict__ Bi,
                    float* __restrict__ Out,
                    int M, int N, int K) {
    const int PQ = K >> 3, NG = K >> 7, ZS = (NG + 7) >> 3;

    __shared__ __align__(16) __bf16 As[BM * BK];
    __shared__ __align__(16) __bf16 Bs[BN * BK];

    const int tid  = threadIdx.x;
    const int lane = tid & 63;
    const int wid  = tid >> 6;

    const int nwg = gridDim.x;
    int bid = blockIdx.x;
    if ((nwg & 7) == 0) {
        const int cpx = nwg >> 3;
        bid = (bid & 7) * cpx + (bid >> 3);
    }
    const int nbn  = N / BN;
    const int brow = (bid / nbn) * BM;
    const int bcol = (bid % nbn) * BN;

    const int wm = wid >> 1;
    const int wn = wid & 1;

    f32x4 acc[4][4];
#pragma unroll
    for (int i = 0; i < 4; ++i)
#pragma unroll
        for (int j = 0; j < 4; ++j)
            acc[i][j] = {0.f, 0.f, 0.f, 0.f};

    int arow[4], acch[4];
#pragma unroll
    for (int it = 0; it < 4; ++it) {
        const int idx = it * 256 + tid;
        arow[it] = idx >> 3;
        acch[it] = idx & 7;
    }

    const int rb    = tid >> 1;
    const int bhalf = tid & 1;
    const int og    = bcol + rb;
    const int* qwrow = QW + (size_t)og * PQ;
    const int* qzrow = QZ + (size_t)og * ZS;
    const float* srow = S + (size_t)og * NG;

    for (int kk = 0; kk < K; kk += BK) {
        bf16x8 areg[4];
#pragma unroll
        for (int it = 0; it < 4; ++it) {
            const float* gx = X + (size_t)(brow + arow[it]) * K + kk + acch[it] * 8;
            const float4 x0 = *(const float4*)gx;
            const float4 x1 = *(const float4*)(gx + 4);
            areg[it][0] = (__bf16)x0.x; areg[it][1] = (__bf16)x0.y;
            areg[it][2] = (__bf16)x0.z; areg[it][3] = (__bf16)x0.w;
            areg[it][4] = (__bf16)x1.x; areg[it][5] = (__bf16)x1.y;
            areg[it][6] = (__bf16)x1.z; areg[it][7] = (__bf16)x1.w;
        }

        const int4 qv = *(const int4*)(qwrow + (kk >> 3) + bhalf * 4);
        const int g  = kk >> 7;
        const int zq = (qzrow[g >> 3] >> ((g & 7) * 4)) & 15;
        const float sf = srow[g];
        const float zs = (float)zq * sf;
        const int vs[4] = {qv.x, qv.y, qv.z, qv.w};
        bf16x8 wregs[4];
#pragma unroll
        for (int w = 0; w < 4; ++w) {
            const int v = vs[w];
#pragma unroll
            for (int j = 0; j < 8; ++j) {
                const float q = (float)((v >> (4 * j)) & 15);
                wregs[w][j] = (__bf16)(q * sf - zs);
            }
        }

#pragma unroll
        for (int it = 0; it < 4; ++it) {
            const int cs = acch[it] ^ (arow[it] & 7);
            *((bf16x8*)(As + (size_t)arow[it] * BK + cs * 8)) = areg[it];
        }
#pragma unroll
        for (int w = 0; w < 4; ++w) {
            const int cs = (bhalf * 4 + w) ^ (rb & 7);
            *((bf16x8*)(Bs + (size_t)rb * BK + cs * 8)) = wregs[w];
        }

        __syncthreads();

#pragma unroll
        for (int ks = 0; ks < 2; ++ks) {
            bf16x8 af[4], bfr[4];
#pragma unroll
            for (int mi = 0; mi < 4; ++mi) {
                const int row = wm * 64 + mi * 16 + (lane & 15);
                const int cs  = (ks * 4 + (lane >> 4)) ^ (row & 7);
                af[mi] = *((const bf16x8*)(As + (size_t)row * BK + cs * 8));
            }
#pragma unroll
            for (int ni = 0; ni < 4; ++ni) {
                const int row = wn * 64 + ni * 16 + (lane & 15);
                const int cs  = (ks * 4 + (lane >> 4)) ^ (row & 7);
                bfr[ni] = *((const bf16x8*)(Bs + (size_t)row * BK + cs * 8));
            }
#pragma unroll
            for (int mi = 0; mi < 4; ++mi)
#pragma unroll
                for (int ni = 0; ni < 4; ++ni)
                    acc[mi][ni] = __builtin_amdgcn_mfma_f32_16x16x32_bf16(
                        af[mi], bfr[ni], acc[mi][ni], 0, 0, 0);
        }
        __syncthreads();
    }

    const int cr0 = brow + wm * 64;
    const int cc0 = bcol + wn * 64;
#pragma unroll
    for (int ni = 0; ni < 4; ++ni) {
        const int col = cc0 + ni * 16 + (lane & 15);
        const float bv = Bi[col];
#pragma unroll
        for (int mi = 0; mi < 4; ++mi) {
#pragma unroll
            for (int r = 0; r < 4; ++r) {
                const int row = cr0 + mi * 16 + (lane >> 4) * 4 + r;
                Out[(size_t)row * N + col] = acc[mi][ni][r] + bv;
            }
        }
    }
}

extern "C" void kernel_launch(void* const* d_in, const int* in_sizes, int n_in,
                              void* d_out, int out_size, void* d_ws, size_t ws_size,
                              hipStream_t stream) {
    const float* X  = (const float*)d_in[0];
    const int*   QW = (const int*)d_in[1];
    const int*   QZ = (const int*)d_in[2];
    const float* S  = (const float*)d_in[3];
    const float* Bi = (const float*)d_in[4];
    float*       Out = (float*)d_out;

    const int O = in_sizes[4];           // 11008
    const int K = in_sizes[1] / O * 8;   // 4096
    const int M = in_sizes[0] / K;       // 8192
    const int NG = K / 128;

    // ws layout: Xq [M*K i8] | sx [M f32] | Wq [O*K i8] | St [NG*O f32]
    const size_t oXq = 0;
    const size_t oSx = (size_t)M * K;
    const size_t oWq = oSx + (size_t)M * 4;
    const size_t oSt = oWq + (size_t)O * K;
    const size_t need = oSt + (size_t)NG * O * 4;

    const bool shapes_ok = (M % 256 == 0) && (O % 128 == 0) &&
                           (K % 256 == 0) && (NG >= 4) &&
                           (oWq % 16 == 0) && (oSt % 16 == 0);

    if (ws_size >= need && shapes_ok) {
        int8_t* Xq = (int8_t*)d_ws + oXq;
        float*  sx = (float*)((char*)d_ws + oSx);
        int8_t* Wq = (int8_t*)d_ws + oWq;
        float*  St = (float*)((char*)d_ws + oSt);
        quant_x<<<M, 256, 0, stream>>>(X, Xq, sx, K);
        quant_w<<<O, K / 32, 0, stream>>>(QW, QZ, Wq, O, K);
        tr_s<<<(O * NG + 255) / 256, 256, 0, stream>>>(S, St, O, NG);
        const int grid = (M / 256) * (O / 128);   // 32*86 = 2752
        gemm_i8v4<<<grid, 512, 0, stream>>>(Xq, sx, Wq, St, Bi, Out, M, O, K);
    } else {
        const int grid = (M / BM) * (O / BN);
        awq_gemm_fused<<<grid, 256, 0, stream>>>(X, QW, QZ, S, Bi, Out, M, O, K);
    }
}

// Round 15
// 728.729 us; speedup vs baseline: 1.8330x; 1.0362x over previous
//
#include <hip/hip_runtime.h>
#include <hip/hip_bf16.h>
#include <stdint.h>

typedef __attribute__((ext_vector_type(8))) __bf16 bf16x8;
typedef __attribute__((ext_vector_type(4))) float f32x4;
typedef __attribute__((ext_vector_type(4))) int   i32x4;

#define BM 128
#define BN 128
#define BK 64

// i8 GEMM geometry (r9-verified best): 256x128 block, K-step 128 (= one AWQ group), ring-3 LDS
#define IBM 256
#define IBN 128
#define IBK 128

__device__ inline void gload_lds16(const void* g, void* l) {
    __builtin_amdgcn_global_load_lds(
        (const __attribute__((address_space(1))) uint32_t*)g,
        (__attribute__((address_space(3))) uint32_t*)l, 16, 0, 0);
}

// ---------------- pass 1a: X f32 -> per-row int8 + scale ----------------
__global__ __launch_bounds__(256)
void quant_x(const float* __restrict__ X, int8_t* __restrict__ Xq,
             float* __restrict__ sx, int K) {
    const int row = blockIdx.x;
    const int tid = threadIdx.x;
    const float* base = X + (size_t)row * K;
    __shared__ float wred[4];

    float am = 0.f;
    for (int b = tid * 16; b < K; b += 256 * 16) {
#pragma unroll
        for (int c = 0; c < 4; ++c) {
            const float4 v = *(const float4*)(base + b + c * 4);
            am = fmaxf(am, fmaxf(fmaxf(fabsf(v.x), fabsf(v.y)),
                                 fmaxf(fabsf(v.z), fabsf(v.w))));
        }
    }
#pragma unroll
    for (int off = 32; off >= 1; off >>= 1)
        am = fmaxf(am, __shfl_xor(am, off));
    if ((tid & 63) == 0) wred[tid >> 6] = am;
    __syncthreads();
    am = fmaxf(fmaxf(wred[0], wred[1]), fmaxf(wred[2], wred[3]));

    const float inv = am > 0.f ? 127.f / am : 0.f;
    for (int b = tid * 16; b < K; b += 256 * 16) {
        int w[4];
#pragma unroll
        for (int c = 0; c < 4; ++c) {
            const float4 v = *(const float4*)(base + b + c * 4);
            const int b0 = __float2int_rn(v.x * inv) & 0xFF;
            const int b1 = __float2int_rn(v.y * inv) & 0xFF;
            const int b2 = __float2int_rn(v.z * inv) & 0xFF;
            const int b3 = __float2int_rn(v.w * inv) & 0xFF;
            w[c] = b0 | (b1 << 8) | (b2 << 16) | (b3 << 24);
        }
        *(int4*)(Xq + (size_t)row * K + b) = make_int4(w[0], w[1], w[2], w[3]);
    }
    if (tid == 0) sx[row] = am > 0.f ? am / 127.f : 0.f;
}

// ---------------- pass 1b: W -> int8 (q - z), exact ----------------
__global__ __launch_bounds__(128)
void quant_w(const int* __restrict__ QW, const int* __restrict__ QZ,
             int8_t* __restrict__ Wq, int N, int K) {
    const int PQ = K >> 3, NG = K >> 7, ZS = (NG + 7) >> 3;
    const int o = blockIdx.x;
    const int c = threadIdx.x;            // 0..K/32-1
    const int g = c >> 2;
    const int zq = (QZ[(size_t)o * ZS + (g >> 3)] >> ((g & 7) * 4)) & 15;
    const int4 qv = *(const int4*)(QW + (size_t)o * PQ + c * 4);
    const int vs[4] = {qv.x, qv.y, qv.z, qv.w};
    int words[8];
#pragma unroll
    for (int w = 0; w < 4; ++w) {
        const int v = vs[w];
        int w0 = 0, w1 = 0;
#pragma unroll
        for (int j = 0; j < 4; ++j)
            w0 |= ((((v >> (4 * j)) & 15) - zq) & 0xFF) << (8 * j);
#pragma unroll
        for (int j = 0; j < 4; ++j)
            w1 |= ((((v >> (4 * (j + 4))) & 15) - zq) & 0xFF) << (8 * j);
        words[w * 2] = w0; words[w * 2 + 1] = w1;
    }
    int8_t* dst = Wq + (size_t)o * K + c * 32;
    *(int4*)dst        = make_int4(words[0], words[1], words[2], words[3]);
    *(int4*)(dst + 16) = make_int4(words[4], words[5], words[6], words[7]);
}

// ---------------- pass 1c: scales [O][NG] f32 -> [NG][O] ----------------
__global__ __launch_bounds__(256)
void tr_s(const float* __restrict__ S, float* __restrict__ St, int N, int NG) {
    const int idx = blockIdx.x * 256 + threadIdx.x;
    if (idx >= N * NG) return;
    const int g = idx / N, o = idx % N;
    St[idx] = S[(size_t)o * NG + g];
}

// ---------------- pass 2: i8 GEMM (r9 structure, de-fragmented scheduling) ----------------
// 512 thr = 8 waves (4 wm x 2 wn), wave tile 64x64 = 4x4 frags of 16x16.
// vs r9 (686 us): REMOVED manual asm lgkmcnt(0)+sched_barrier inside MFMA
// clusters (compiler-generated ds_reads get precise compiler lgkmcnt waits -
// m97 evidence) and SBARs around scale loads / STAGE / setprio(0). m141 lesson:
// order-pinning defeats the compiler's own scheduling. KEPT: all vmcnt gates
// (+1 SBAR each - they guard the gload_lds->ds_read RAW the compiler can't
// track), barriers, setprio, ring-3 147KB LDS, zero-conflict chunk-XOR swizzle.
__global__ __launch_bounds__(512, 2)
void gemm_i8(const int8_t* __restrict__ Aq, const float* __restrict__ sx,
             const int8_t* __restrict__ Bq, const float* __restrict__ St,
             const float* __restrict__ Bi, float* __restrict__ Out,
             int M, int N, int K) {
    __shared__ __align__(16) char lds[3 * 49152];

    const int tid  = threadIdx.x;
    const int lane = tid & 63;
    const int wid  = tid >> 6;
    const int wm   = wid >> 1;   // 0..3
    const int wn   = wid & 1;    // 0..1

    int bid = blockIdx.x;
    {
        const int nwg = gridDim.x;
        if ((nwg & 7) == 0) {
            const int cpx = nwg >> 3;
            bid = (bid & 7) * cpx + (bid >> 3);
        }
    }
    const int nbm  = M / IBM;
    const int brow = (bid % nbm) * IBM;   // col-major tile order: B-panel L2-resident
    const int bcol = (bid / nbm) * IBN;

    // staging: A 2048 16B-slots (4/thread), B 1024 (2/thread).
    // slot s: row = s>>3, c_lds = s&7, global chunk c_g = c_lds ^ (row&7).
    int aro[4], acg[4], bro[2], bcg[2];
#pragma unroll
    for (int it = 0; it < 4; ++it) {
        const int s = it * 512 + tid;
        aro[it] = s >> 3; acg[it] = (s & 7) ^ ((s >> 3) & 7);
    }
#pragma unroll
    for (int it = 0; it < 2; ++it) {
        const int s = it * 512 + tid;
        bro[it] = s >> 3; bcg[it] = (s & 7) ^ ((s >> 3) & 7);
    }
    const int8_t* gA[4]; const int8_t* gB[2];
#pragma unroll
    for (int it = 0; it < 4; ++it) gA[it] = Aq + (size_t)(brow + aro[it]) * K + acg[it] * 16;
#pragma unroll
    for (int it = 0; it < 2; ++it) gB[it] = Bq + (size_t)(bcol + bro[it]) * K + bcg[it] * 16;

    const int rA15 = lane & 15;
    const int q4   = lane >> 4;

    f32x4 facc[4][4];
#pragma unroll
    for (int i = 0; i < 4; ++i)
#pragma unroll
        for (int j = 0; j < 4; ++j)
            facc[i][j] = {0.f, 0.f, 0.f, 0.f};

    const int NT = K / IBK;

#define SBAR __builtin_amdgcn_sched_barrier(0)
#define ABUF(RR_) (lds + (RR_) * 49152)
#define BBUF(RR_) (lds + (RR_) * 49152 + 32768)

#define STAGE(RR_, T_)                                                           \
    do {                                                                         \
        gload_lds16(gA[0] + (size_t)(T_) * IBK, ABUF(RR_) + (0 * 512 + wid * 64) * 16); \
        gload_lds16(gA[1] + (size_t)(T_) * IBK, ABUF(RR_) + (1 * 512 + wid * 64) * 16); \
        gload_lds16(gA[2] + (size_t)(T_) * IBK, ABUF(RR_) + (2 * 512 + wid * 64) * 16); \
        gload_lds16(gA[3] + (size_t)(T_) * IBK, ABUF(RR_) + (3 * 512 + wid * 64) * 16); \
        gload_lds16(gB[0] + (size_t)(T_) * IBK, BBUF(RR_) + (0 * 512 + wid * 64) * 16); \
        gload_lds16(gB[1] + (size_t)(T_) * IBK, BBUF(RR_) + (1 * 512 + wid * 64) * 16); \
    } while (0)

    // fragment read: row r, global chunk c = ks*4 + q4; byte = r*128 + (c^(r&7))*16
#define LDA(RR_, MI, KS)                                                         \
    (*(const i32x4*)(ABUF(RR_) + (wm * 64 + (MI) * 16 + rA15) * 128 +            \
                     ((((KS) * 4 + q4) ^ ((wm * 64 + (MI) * 16 + rA15) & 7)) * 16)))
#define LDB(RR_, NI, KS)                                                         \
    (*(const i32x4*)(BBUF(RR_) + (wn * 64 + (NI) * 16 + rA15) * 128 +            \
                     ((((KS) * 4 + q4) ^ ((wn * 64 + (NI) * 16 + rA15) & 7)) * 16)))

#define MFMA16(RR_, KS_, FIRST_)                                                 \
    do {                                                                         \
        i32x4 b0 = LDB(RR_, 0, KS_), b1 = LDB(RR_, 1, KS_);                      \
        i32x4 b2 = LDB(RR_, 2, KS_), b3 = LDB(RR_, 3, KS_);                      \
        i32x4 a0 = LDA(RR_, 0, KS_), a1 = LDA(RR_, 1, KS_);                      \
        i32x4 a2 = LDA(RR_, 2, KS_), a3 = LDA(RR_, 3, KS_);                      \
        __builtin_amdgcn_s_setprio(1);                                           \
        if (FIRST_) {                                                            \
            const i32x4 zz = {0, 0, 0, 0};                                       \
            iacc[0][0] = __builtin_amdgcn_mfma_i32_16x16x64_i8(a0, b0, zz, 0, 0, 0); \
            iacc[0][1] = __builtin_amdgcn_mfma_i32_16x16x64_i8(a0, b1, zz, 0, 0, 0); \
            iacc[0][2] = __builtin_amdgcn_mfma_i32_16x16x64_i8(a0, b2, zz, 0, 0, 0); \
            iacc[0][3] = __builtin_amdgcn_mfma_i32_16x16x64_i8(a0, b3, zz, 0, 0, 0); \
            iacc[1][0] = __builtin_amdgcn_mfma_i32_16x16x64_i8(a1, b0, zz, 0, 0, 0); \
            iacc[1][1] = __builtin_amdgcn_mfma_i32_16x16x64_i8(a1, b1, zz, 0, 0, 0); \
            iacc[1][2] = __builtin_amdgcn_mfma_i32_16x16x64_i8(a1, b2, zz, 0, 0, 0); \
            iacc[1][3] = __builtin_amdgcn_mfma_i32_16x16x64_i8(a1, b3, zz, 0, 0, 0); \
            iacc[2][0] = __builtin_amdgcn_mfma_i32_16x16x64_i8(a2, b0, zz, 0, 0, 0); \
            iacc[2][1] = __builtin_amdgcn_mfma_i32_16x16x64_i8(a2, b1, zz, 0, 0, 0); \
            iacc[2][2] = __builtin_amdgcn_mfma_i32_16x16x64_i8(a2, b2, zz, 0, 0, 0); \
            iacc[2][3] = __builtin_amdgcn_mfma_i32_16x16x64_i8(a2, b3, zz, 0, 0, 0); \
            iacc[3][0] = __builtin_amdgcn_mfma_i32_16x16x64_i8(a3, b0, zz, 0, 0, 0); \
            iacc[3][1] = __builtin_amdgcn_mfma_i32_16x16x64_i8(a3, b1, zz, 0, 0, 0); \
            iacc[3][2] = __builtin_amdgcn_mfma_i32_16x16x64_i8(a3, b2, zz, 0, 0, 0); \
            iacc[3][3] = __builtin_amdgcn_mfma_i32_16x16x64_i8(a3, b3, zz, 0, 0, 0); \
        } else {                                                                 \
            iacc[0][0] = __builtin_amdgcn_mfma_i32_16x16x64_i8(a0, b0, iacc[0][0], 0, 0, 0); \
            iacc[0][1] = __builtin_amdgcn_mfma_i32_16x16x64_i8(a0, b1, iacc[0][1], 0, 0, 0); \
            iacc[0][2] = __builtin_amdgcn_mfma_i32_16x16x64_i8(a0, b2, iacc[0][2], 0, 0, 0); \
            iacc[0][3] = __builtin_amdgcn_mfma_i32_16x16x64_i8(a0, b3, iacc[0][3], 0, 0, 0); \
            iacc[1][0] = __builtin_amdgcn_mfma_i32_16x16x64_i8(a1, b0, iacc[1][0], 0, 0, 0); \
            iacc[1][1] = __builtin_amdgcn_mfma_i32_16x16x64_i8(a1, b1, iacc[1][1], 0, 0, 0); \
            iacc[1][2] = __builtin_amdgcn_mfma_i32_16x16x64_i8(a1, b2, iacc[1][2], 0, 0, 0); \
            iacc[1][3] = __builtin_amdgcn_mfma_i32_16x16x64_i8(a1, b3, iacc[1][3], 0, 0, 0); \
            iacc[2][0] = __builtin_amdgcn_mfma_i32_16x16x64_i8(a2, b0, iacc[2][0], 0, 0, 0); \
            iacc[2][1] = __builtin_amdgcn_mfma_i32_16x16x64_i8(a2, b1, iacc[2][1], 0, 0, 0); \
            iacc[2][2] = __builtin_amdgcn_mfma_i32_16x16x64_i8(a2, b2, iacc[2][2], 0, 0, 0); \
            iacc[2][3] = __builtin_amdgcn_mfma_i32_16x16x64_i8(a2, b3, iacc[2][3], 0, 0, 0); \
            iacc[3][0] = __builtin_amdgcn_mfma_i32_16x16x64_i8(a3, b0, iacc[3][0], 0, 0, 0); \
            iacc[3][1] = __builtin_amdgcn_mfma_i32_16x16x64_i8(a3, b1, iacc[3][1], 0, 0, 0); \
            iacc[3][2] = __builtin_amdgcn_mfma_i32_16x16x64_i8(a3, b2, iacc[3][2], 0, 0, 0); \
            iacc[3][3] = __builtin_amdgcn_mfma_i32_16x16x64_i8(a3, b3, iacc[3][3], 0, 0, 0); \
        }                                                                        \
        __builtin_amdgcn_s_setprio(0);                                           \
    } while (0)

#define TILE(R_, T_, TOPSTR_, CVTSTR_, STG_)                                     \
    do {                                                                         \
        asm volatile("s_waitcnt vmcnt(" TOPSTR_ ")" ::: "memory"); SBAR;         \
        __builtin_amdgcn_s_barrier(); SBAR;                                      \
        const size_t so = (size_t)(T_) * N + bcol + wn * 64 + rA15;              \
        const float sv0 = St[so +  0], sv1 = St[so + 16];                        \
        const float sv2 = St[so + 32], sv3 = St[so + 48];                        \
        STG_;                                                                    \
        i32x4 iacc[4][4];                                                        \
        MFMA16(R_, 0, true);                                                     \
        MFMA16(R_, 1, false);                                                    \
        asm volatile("s_waitcnt vmcnt(" CVTSTR_ ")" ::: "memory"); SBAR;         \
        _Pragma("unroll")                                                        \
        for (int mi = 0; mi < 4; ++mi) {                                         \
            _Pragma("unroll")                                                    \
            for (int j = 0; j < 4; ++j) {                                        \
                facc[mi][0][j] += (float)iacc[mi][0][j] * sv0;                   \
                facc[mi][1][j] += (float)iacc[mi][1][j] * sv1;                   \
                facc[mi][2][j] += (float)iacc[mi][2][j] * sv2;                   \
                facc[mi][3][j] += (float)iacc[mi][3][j] * sv3;                   \
            }                                                                    \
        }                                                                        \
    } while (0)

    // prologue: 2 tiles in flight
    STAGE(0, 0);
    STAGE(1, 1);

    for (int t = 0; t < NT - 2; ++t) {
        const int r = t % 3;
        const int r2 = (t + 2) % 3;
        TILE(r, t, "6", "6", STAGE(r2, t + 2));
    }
    TILE(((NT - 2) % 3), NT - 2, "6", "0", (void)0);
    TILE(((NT - 1) % 3), NT - 1, "0", "0", (void)0);

#undef TILE
#undef MFMA16
#undef LDB
#undef LDA
#undef STAGE
#undef BBUF
#undef ABUF
#undef SBAR

    // epilogue: C frag col=lane&15, row=(lane>>4)*4+r; out = sx[row]*acc + bias
    const int cr0 = brow + wm * 64;
    const int cc0 = bcol + wn * 64;
#pragma unroll
    for (int ni = 0; ni < 4; ++ni) {
        const int col = cc0 + ni * 16 + rA15;
        const float bv = Bi[col];
#pragma unroll
        for (int mi = 0; mi < 4; ++mi) {
#pragma unroll
            for (int r = 0; r < 4; ++r) {
                const int row = cr0 + mi * 16 + q4 * 4 + r;
                Out[(size_t)row * N + col] = sx[row] * facc[mi][ni][r] + bv;
            }
        }
    }
}

// ---------------- fallback: fused kernel (ws too small / odd shapes) ----------------
__global__ __launch_bounds__(256, 3)
void awq_gemm_fused(const float* __restrict__ X,
                    const int* __restrict__ QW,
                    const int* __restrict__ QZ,
                    const float* __restrict__ S,
                    const float* __restrict__ Bi,
                    float* __restrict__ Out,
                    int M, int N, int K) {
    const int PQ = K >> 3, NG = K >> 7, ZS = (NG + 7) >> 3;

    __shared__ __align__(16) __bf16 As[BM * BK];
    __shared__ __align__(16) __bf16 Bs[BN * BK];

    const int tid  = threadIdx.x;
    const int lane = tid & 63;
    const int wid  = tid >> 6;

    const int nwg = gridDim.x;
    int bid = blockIdx.x;
    if ((nwg & 7) == 0) {
        const int cpx = nwg >> 3;
        bid = (bid & 7) * cpx + (bid >> 3);
    }
    const int nbn  = N / BN;
    const int brow = (bid / nbn) * BM;
    const int bcol = (bid % nbn) * BN;

    const int wm = wid >> 1;
    const int wn = wid & 1;

    f32x4 acc[4][4];
#pragma unroll
    for (int i = 0; i < 4; ++i)
#pragma unroll
        for (int j = 0; j < 4; ++j)
            acc[i][j] = {0.f, 0.f, 0.f, 0.f};

    int arow[4], acch[4];
#pragma unroll
    for (int it = 0; it < 4; ++it) {
        const int idx = it * 256 + tid;
        arow[it] = idx >> 3;
        acch[it] = idx & 7;
    }

    const int rb    = tid >> 1;
    const int bhalf = tid & 1;
    const int og    = bcol + rb;
    const int* qwrow = QW + (size_t)og * PQ;
    const int* qzrow = QZ + (size_t)og * ZS;
    const float* srow = S + (size_t)og * NG;

    for (int kk = 0; kk < K; kk += BK) {
        bf16x8 areg[4];
#pragma unroll
        for (int it = 0; it < 4; ++it) {
            const float* gx = X + (size_t)(brow + arow[it]) * K + kk + acch[it] * 8;
            const float4 x0 = *(const float4*)gx;
            const float4 x1 = *(const float4*)(gx + 4);
            areg[it][0] = (__bf16)x0.x; areg[it][1] = (__bf16)x0.y;
            areg[it][2] = (__bf16)x0.z; areg[it][3] = (__bf16)x0.w;
            areg[it][4] = (__bf16)x1.x; areg[it][5] = (__bf16)x1.y;
            areg[it][6] = (__bf16)x1.z; areg[it][7] = (__bf16)x1.w;
        }

        const int4 qv = *(const int4*)(qwrow + (kk >> 3) + bhalf * 4);
        const int g  = kk >> 7;
        const int zq = (qzrow[g >> 3] >> ((g & 7) * 4)) & 15;
        const float sf = srow[g];
        const float zs = (float)zq * sf;
        const int vs[4] = {qv.x, qv.y, qv.z, qv.w};
        bf16x8 wregs[4];
#pragma unroll
        for (int w = 0; w < 4; ++w) {
            const int v = vs[w];
#pragma unroll
            for (int j = 0; j < 8; ++j) {
                const float q = (float)((v >> (4 * j)) & 15);
                wregs[w][j] = (__bf16)(q * sf - zs);
            }
        }

#pragma unroll
        for (int it = 0; it < 4; ++it) {
            const int cs = acch[it] ^ (arow[it] & 7);
            *((bf16x8*)(As + (size_t)arow[it] * BK + cs * 8)) = areg[it];
        }
#pragma unroll
        for (int w = 0; w < 4; ++w) {
            const int cs = (bhalf * 4 + w) ^ (rb & 7);
            *((bf16x8*)(Bs + (size_t)rb * BK + cs * 8)) = wregs[w];
        }

        __syncthreads();

#pragma unroll
        for (int ks = 0; ks < 2; ++ks) {
            bf16x8 af[4], bfr[4];
#pragma unroll
            for (int mi = 0; mi < 4; ++mi) {
                const int row = wm * 64 + mi * 16 + (lane & 15);
                const int cs  = (ks * 4 + (lane >> 4)) ^ (row & 7);
                af[mi] = *((const bf16x8*)(As + (size_t)row * BK + cs * 8));
            }
#pragma unroll
            for (int ni = 0; ni < 4; ++ni) {
                const int row = wn * 64 + ni * 16 + (lane & 15);
                const int cs  = (ks * 4 + (lane >> 4)) ^ (row & 7);
                bfr[ni] = *((const bf16x8*)(Bs + (size_t)row * BK + cs * 8));
            }
#pragma unroll
            for (int mi = 0; mi < 4; ++mi)
#pragma unroll
                for (int ni = 0; ni < 4; ++ni)
                    acc[mi][ni] = __builtin_amdgcn_mfma_f32_16x16x32_bf16(
                        af[mi], bfr[ni], acc[mi][ni], 0, 0, 0);
        }
        __syncthreads();
    }

    const int cr0 = brow + wm * 64;
    const int cc0 = bcol + wn * 64;
#pragma unroll
    for (int ni = 0; ni < 4; ++ni) {
        const int col = cc0 + ni * 16 + (lane & 15);
        const float bv = Bi[col];
#pragma unroll
        for (int mi = 0; mi < 4; ++mi) {
#pragma unroll
            for (int r = 0; r < 4; ++r) {
                const int row = cr0 + mi * 16 + (lane >> 4) * 4 + r;
                Out[(size_t)row * N + col] = acc[mi][ni][r] + bv;
            }
        }
    }
}

extern "C" void kernel_launch(void* const* d_in, const int* in_sizes, int n_in,
                              void* d_out, int out_size, void* d_ws, size_t ws_size,
                              hipStream_t stream) {
    const float* X  = (const float*)d_in[0];
    const int*   QW = (const int*)d_in[1];
    const int*   QZ = (const int*)d_in[2];
    const float* S  = (const float*)d_in[3];
    const float* Bi = (const float*)d_in[4];
    float*       Out = (float*)d_out;

    const int O = in_sizes[4];           // 11008
    const int K = in_sizes[1] / O * 8;   // 4096
    const int M = in_sizes[0] / K;       // 8192
    const int NG = K / 128;

    // ws layout: Xq [M*K i8] | sx [M f32] | Wq [O*K i8] | St [NG*O f32]
    const size_t oXq = 0;
    const size_t oSx = (size_t)M * K;
    const size_t oWq = oSx + (size_t)M * 4;
    const size_t oSt = oWq + (size_t)O * K;
    const size_t need = oSt + (size_t)NG * O * 4;

    const bool shapes_ok = (M % IBM == 0) && (O % IBN == 0) &&
                           (K % IBK == 0) && (K / IBK >= 4) &&
                           (oWq % 16 == 0) && (oSt % 16 == 0);

    if (ws_size >= need && shapes_ok) {
        int8_t* Xq = (int8_t*)d_ws + oXq;
        float*  sx = (float*)((char*)d_ws + oSx);
        int8_t* Wq = (int8_t*)d_ws + oWq;
        float*  St = (float*)((char*)d_ws + oSt);
        quant_x<<<M, 256, 0, stream>>>(X, Xq, sx, K);
        quant_w<<<O, K / 32, 0, stream>>>(QW, QZ, Wq, O, K);
        tr_s<<<(O * NG + 255) / 256, 256, 0, stream>>>(S, St, O, NG);
        const int grid = (M / IBM) * (O / IBN);   // 32*86 = 2752
        gemm_i8<<<grid, 512, 0, stream>>>(Xq, sx, Wq, St, Bi, Out, M, O, K);
    } else {
        const int grid = (M / BM) * (O / BN);
        awq_gemm_fused<<<grid, 256, 0, stream>>>(X, QW, QZ, S, Bi, Out, M, O, K);
    }
}